// Round 9
// baseline (462.293 us; speedup 1.0000x reference)
//
#include <hip/hip_runtime.h>

#define NN 100000
#define FF 128
#define HH 64
#define CC 16
#define EE 1000000
#define NSEG (2*NN)                 // segments: [0,NN) = fwd, [NN,2NN) = rev
#define BSH 11                      // bucket = d >> 11 (2048 dsts/bucket)
#define BKD  (1 << BSH)
#define NBUK ((NSEG + BKD - 1) / BKD)   // 98
#define EPB 4096                    // edges per fillA/bucket_count block
#define P1BLK ((2*EE + EPB - 1) / EPB)

typedef __bf16 bf16;
typedef __attribute__((ext_vector_type(8))) __bf16 bf16x8;
typedef __attribute__((ext_vector_type(4))) __bf16 bf16x4;
typedef __attribute__((ext_vector_type(4))) float f32x4;

__device__ __forceinline__ float fsig(float t)  { return 1.0f/(1.0f+__expf(-t)); }
__device__ __forceinline__ float ftanh(float t) { return 1.0f - 2.0f/(__expf(2.0f*t)+1.0f); }

// pack (src, w>=0) into 4 B: src(17 bits) << 15 | bf16(w) sans sign (15 bits)
__device__ __forceinline__ unsigned pack_sw(int s, float w) {
    unsigned short u = __builtin_bit_cast(unsigned short, (bf16)w);
    return ((unsigned)s << 15) | (u & 0x7FFFu);
}

// ---- Combined weights in bf16 + bf16 copies of W_first / W_lin1 / W_out
__global__ void precomp_kernel(const float* __restrict__ W_ih, const float* __restrict__ b_ih,
                               const float* __restrict__ Wc1,  const float* __restrict__ bc1,
                               const float* __restrict__ Wc2,  const float* __restrict__ bc2,
                               const float* __restrict__ W_hh, const float* __restrict__ W_first,
                               const float* __restrict__ W_lin1, const float* __restrict__ W_out,
                               bf16* __restrict__ W1bf, float* __restrict__ b1,
                               bf16* __restrict__ W2bf, float* __restrict__ b2,
                               bf16* __restrict__ Whbf, bf16* __restrict__ Wfbf,
                               bf16* __restrict__ Wlbf, bf16* __restrict__ Wobf)
{
    int idx = blockIdx.x*blockDim.x + threadIdx.x;
    const int t0 = 192*128;          // W1/W2
    const int t1 = t0 + 192;         // b1/b2
    const int t2 = t1 + 192*64;      // Whbf
    const int t3 = t2 + 64*128;      // Wfbf
    const int t4 = t3 + 64*64;       // Wlbf
    const int t5 = t4 + 16*64;       // Wobf
    if (idx < t0) {
        int j = idx >> 7, k = idx & 127;
        float s1 = 0.f, s2 = 0.f;
        for (int m=0; m<64; ++m) {
            float wih = W_ih[j*64+m];
            s1 += wih * Wc1[m*128+k];
            s2 += wih * Wc2[m*128+k];
        }
        W1bf[idx] = (bf16)s1; W2bf[idx] = (bf16)s2;
    } else if (idx < t1) {
        int j = idx - t0;
        float s1 = b_ih[j], s2 = b_ih[j];
        for (int m=0; m<64; ++m) {
            float wih = W_ih[j*64+m];
            s1 += wih * bc1[m];
            s2 += wih * bc2[m];
        }
        b1[j] = s1; b2[j] = s2;
    } else if (idx < t2) {
        int i = idx - t1;  Whbf[i] = (bf16)W_hh[i];
    } else if (idx < t3) {
        int i = idx - t2;  Wfbf[i] = (bf16)W_first[i];
    } else if (idx < t4) {
        int i = idx - t3;  Wlbf[i] = (bf16)W_lin1[i];
    } else if (idx < t5) {
        int i = idx - t4;  Wobf[i] = (bf16)W_out[i];
    }
}

// ================= CSR build: bucketed 2-phase sort =================

__global__ __launch_bounds__(256) void bucket_count_kernel(const int* __restrict__ ei,
                                                           const int* __restrict__ ei_re,
                                                           int* __restrict__ bkcnt)
{
    __shared__ int hist[NBUK];
    const int t = threadIdx.x;
    for (int i=t; i<NBUK; i+=256) hist[i] = 0;
    __syncthreads();
    const long e0 = (long)blockIdx.x * EPB;
    #pragma unroll
    for (int it=0; it<16; ++it) {
        long e = e0 + it*256 + t;
        int d = -1;
        if (e < EE)        d = ei[EE + e];
        else if (e < 2*EE) d = NN + ei_re[EE + (e - EE)];
        if (d >= 0) atomicAdd(&hist[d >> BSH], 1);
    }
    __syncthreads();
    for (int i=t; i<NBUK; i+=256) if (hist[i]) atomicAdd(&bkcnt[i], hist[i]);
}

__global__ void bucket_scan_kernel(const int* __restrict__ bkcnt,
                                   int* __restrict__ bkbase, int* __restrict__ bkcur,
                                   int* __restrict__ rp)
{
    if (threadIdx.x == 0) {
        int acc = 0;
        for (int i=0; i<NBUK; ++i) { bkbase[i] = acc; bkcur[i] = acc; acc += bkcnt[i]; }
        bkbase[NBUK] = acc;          // = 2E
        rp[NSEG] = 2*EE;
    }
}

__global__ __launch_bounds__(256) void fillA_kernel(const int* __restrict__ ei,
                                                    const float* __restrict__ ew,
                                                    const int* __restrict__ ei_re,
                                                    const float* __restrict__ ew_re,
                                                    int* __restrict__ bkcur,
                                                    int* __restrict__ tmp_d,
                                                    unsigned* __restrict__ tmp_p)
{
    __shared__ int hist[NBUK];
    __shared__ int base[NBUK];
    const int t = threadIdx.x;
    for (int i=t; i<NBUK; i+=256) hist[i] = 0;
    __syncthreads();
    const long e0 = (long)blockIdx.x * EPB;
    int pr[16];
    #pragma unroll
    for (int it=0; it<16; ++it) {
        long e = e0 + it*256 + t;
        int d = -1;
        if (e < EE)        d = ei[EE + e];
        else if (e < 2*EE) d = NN + ei_re[EE + (e - EE)];
        if (d >= 0) {
            int b = d >> BSH;
            int r = atomicAdd(&hist[b], 1);
            pr[it] = (b << 16) | r;
        } else pr[it] = -1;
    }
    __syncthreads();
    for (int i=t; i<NBUK; i+=256) base[i] = atomicAdd(&bkcur[i], hist[i]);
    __syncthreads();
    #pragma unroll
    for (int it=0; it<16; ++it) {
        if (pr[it] < 0) continue;
        long e = e0 + it*256 + t;
        int d, s; float w;
        if (e < EE) { d = ei[EE+e]; s = ei[e]; w = ew[e]; }
        else { long j = e - EE; d = NN + ei_re[EE+j]; s = ei_re[j]; w = ew_re[j]; }
        int pos = base[pr[it] >> 16] + (pr[it] & 0xFFFF);
        tmp_d[pos] = d;
        tmp_p[pos] = pack_sw(s, w);
    }
}

__global__ __launch_bounds__(1024) void fillB_kernel(const int* __restrict__ bkbase,
                                                     const int* __restrict__ tmp_d,
                                                     const unsigned* __restrict__ tmp_p,
                                                     unsigned* __restrict__ edata,
                                                     int* __restrict__ rp)
{
    __shared__ int cntL[BKD];      // counts -> later global cursors
    __shared__ int scanL[1024];
    const int t  = threadIdx.x;
    const int b  = blockIdx.x;
    const int d0 = b << BSH;
    const int dn = min(BKD, NSEG - d0);
    const int p0 = bkbase[b];
    const int p1 = bkbase[b+1];
    for (int i=t; i<BKD; i+=1024) cntL[i] = 0;
    __syncthreads();
    for (int pos = p0 + t; pos < p1; pos += 1024)
        atomicAdd(&cntL[tmp_d[pos] - d0], 1);
    __syncthreads();
    int a0 = cntL[2*t], a1 = cntL[2*t+1];
    int ps = a0 + a1;
    scanL[t] = ps;
    __syncthreads();
    #pragma unroll
    for (int off=1; off<1024; off<<=1) {
        int x = (t>=off) ? scanL[t-off] : 0;
        __syncthreads();
        scanL[t] += x;
        __syncthreads();
    }
    int g0 = p0 + scanL[t] - ps;
    int g1 = g0 + a0;
    if (2*t   < dn) rp[d0 + 2*t]   = g0;
    if (2*t+1 < dn) rp[d0 + 2*t+1] = g1;
    cntL[2*t]   = g0;
    cntL[2*t+1] = g1;
    __syncthreads();
    for (int pos = p0 + t; pos < p1; pos += 1024) {
        int d = tmp_d[pos];
        int p = atomicAdd(&cntL[d - d0], 1);
        edata[p] = tmp_p[pos];
    }
}

// Quarter-wave gather segment-sum: 16 lanes per edge (bf16x4/lane), 4 edges
// in flight per wave-instruction -> ~2x fewer VALU ops per edge than the
// full-wave variant (which measured VALUBusy=86%, VALU-bound).
__global__ __launch_bounds__(256) void csr_prop_kernel(const bf16* __restrict__ X,
    const int* __restrict__ rp, const unsigned* __restrict__ edata,
    bf16* __restrict__ x1, bf16* __restrict__ x2)
{
    int s = blockIdx.x*4 + (threadIdx.x>>6);
    if (s >= NSEG) return;
    const int lane = threadIdx.x & 63;
    const int q  = lane >> 4;      // edge slot 0..3
    const int fl = lane & 15;      // feature group: 4fl .. 4fl+3
    const int e0 = rp[s], e1 = rp[s+1];
    float a0=0.f, a1=0.f, a2=0.f, a3=0.f;
    for (int base = e0; base < e1; base += 4) {
        int e = base + q;
        unsigned p = edata[e < e1 ? e : e0];
        float w = (e < e1) ? __uint_as_float((p & 0x7FFFu) << 16) : 0.f;
        bf16x4 xv = *(const bf16x4*)&X[(long)(p >> 15)*HH + 4*fl];
        a0 += w*(float)xv[0];
        a1 += w*(float)xv[1];
        a2 += w*(float)xv[2];
        a3 += w*(float)xv[3];
    }
    // reduce across the 4 quarters (lanes with equal fl)
    a0 += __shfl_xor(a0, 32); a0 += __shfl_xor(a0, 16);
    a1 += __shfl_xor(a1, 32); a1 += __shfl_xor(a1, 16);
    a2 += __shfl_xor(a2, 32); a2 += __shfl_xor(a2, 16);
    a3 += __shfl_xor(a3, 32); a3 += __shfl_xor(a3, 16);
    if (q == 0) {
        bf16* o = (s < NN) ? &x1[(long)s*HH] : &x2[(long)(s-NN)*HH];
        bf16x4 ov = {(bf16)a0, (bf16)a1, (bf16)a2, (bf16)a3};
        *(bf16x4*)&o[4*fl] = ov;
    }
}

// ================= dense kernels: all MFMA (unchanged) =================

__global__ __launch_bounds__(256, 2) void lin_first_mfma_kernel(
    const float* __restrict__ X, const bf16* __restrict__ Wf,
    const float* __restrict__ b, float* __restrict__ Y, bf16* __restrict__ Ybf)
{
    const int t = threadIdx.x;
    const int w = t >> 6, lane = t & 63, col = lane & 15, quad = lane >> 4;
    bf16x8 B[4];
    #pragma unroll
    for (int ks=0; ks<4; ++ks)
        B[ks] = *(const bf16x8*)&Wf[(16*w+col)*128 + ks*32 + quad*8];
    const float bv = b[16*w + col];
    __shared__ bf16 Alds[32][136];
    const int m_st = t >> 3, c_in = t & 7;
    for (int tb = blockIdx.x*32; tb < NN; tb += gridDim.x*32) {
        const float4* rx = (const float4*)&X[(long)(tb+m_st)*FF];
        #pragma unroll
        for (int it=0; it<4; ++it) {
            int cc = c_in + it*8;
            float4 v = rx[cc];
            bf16x4 bvv = {(bf16)v.x,(bf16)v.y,(bf16)v.z,(bf16)v.w};
            *(bf16x4*)&Alds[m_st][cc*4] = bvv;
        }
        __syncthreads();
        f32x4 acc[2] = {{0.f,0.f,0.f,0.f},{0.f,0.f,0.f,0.f}};
        #pragma unroll
        for (int ks=0; ks<4; ++ks)
            #pragma unroll
            for (int mt=0; mt<2; ++mt) {
                bf16x8 a = *(const bf16x8*)&Alds[mt*16+col][ks*32+quad*8];
                acc[mt] = __builtin_amdgcn_mfma_f32_16x16x32_bf16(a, B[ks], acc[mt], 0,0,0);
            }
        __syncthreads();
        #pragma unroll
        for (int mt=0; mt<2; ++mt)
            #pragma unroll
            for (int r=0; r<4; ++r) {
                long n = tb + mt*16 + quad*4 + r;
                float val = acc[mt][r] + bv;
                Y  [n*HH + 16*w+col] = val;
                Ybf[n*HH + 16*w+col] = (bf16)val;
            }
    }
}

__global__ __launch_bounds__(256, 2) void lin64_mfma_kernel(
    const float* __restrict__ X, const bf16* __restrict__ Wl,
    const float* __restrict__ b, bf16* __restrict__ Ybf)
{
    const int t = threadIdx.x;
    const int w = t >> 6, lane = t & 63, col = lane & 15, quad = lane >> 4;
    bf16x8 B[2];
    #pragma unroll
    for (int ks=0; ks<2; ++ks)
        B[ks] = *(const bf16x8*)&Wl[(16*w+col)*64 + ks*32 + quad*8];
    const float bv = b[16*w + col];
    __shared__ bf16 Alds[32][72];
    const int m_st = t >> 3, c_in = t & 7;
    for (int tb = blockIdx.x*32; tb < NN; tb += gridDim.x*32) {
        const float4* rx = (const float4*)&X[(long)(tb+m_st)*HH];
        #pragma unroll
        for (int it=0; it<2; ++it) {
            int cc = c_in + it*8;
            float4 v = rx[cc];
            bf16x4 bvv = {(bf16)v.x,(bf16)v.y,(bf16)v.z,(bf16)v.w};
            *(bf16x4*)&Alds[m_st][cc*4] = bvv;
        }
        __syncthreads();
        f32x4 acc[2] = {{0.f,0.f,0.f,0.f},{0.f,0.f,0.f,0.f}};
        #pragma unroll
        for (int ks=0; ks<2; ++ks)
            #pragma unroll
            for (int mt=0; mt<2; ++mt) {
                bf16x8 a = *(const bf16x8*)&Alds[mt*16+col][ks*32+quad*8];
                acc[mt] = __builtin_amdgcn_mfma_f32_16x16x32_bf16(a, B[ks], acc[mt], 0,0,0);
            }
        __syncthreads();
        #pragma unroll
        for (int mt=0; mt<2; ++mt)
            #pragma unroll
            for (int r=0; r<4; ++r)
                Ybf[(long)(tb+mt*16+quad*4+r)*HH + 16*w+col] = (bf16)(acc[mt][r] + bv);
    }
}

__global__ __launch_bounds__(256) void out_mfma_kernel(
    const float* __restrict__ X, const bf16* __restrict__ Wo,
    const float* __restrict__ b, float* __restrict__ Y)
{
    const int t = threadIdx.x;
    const int w = t >> 6, lane = t & 63, col = lane & 15, quad = lane >> 4;
    bf16x8 B[2];
    #pragma unroll
    for (int ks=0; ks<2; ++ks)
        B[ks] = *(const bf16x8*)&Wo[col*64 + ks*32 + quad*8];
    const float bv = b[col];
    __shared__ bf16 Alds[128][72];
    const int r_st = t >> 1, sub = t & 1;
    const int tb = blockIdx.x*128;
    {
        const float4* rx = (const float4*)&X[(long)(tb+r_st)*HH];
        #pragma unroll
        for (int it=0; it<8; ++it) {
            int cc = sub*8 + it;
            float4 v = rx[cc];
            bf16x4 bvv = {(bf16)v.x,(bf16)v.y,(bf16)v.z,(bf16)v.w};
            *(bf16x4*)&Alds[r_st][cc*4] = bvv;
        }
    }
    __syncthreads();
    f32x4 acc[2] = {{0.f,0.f,0.f,0.f},{0.f,0.f,0.f,0.f}};
    #pragma unroll
    for (int ks=0; ks<2; ++ks)
        #pragma unroll
        for (int mt=0; mt<2; ++mt) {
            bf16x8 a = *(const bf16x8*)&Alds[w*32 + mt*16 + col][ks*32+quad*8];
            acc[mt] = __builtin_amdgcn_mfma_f32_16x16x32_bf16(a, B[ks], acc[mt], 0,0,0);
        }
    #pragma unroll
    for (int mt=0; mt<2; ++mt) {
        #pragma unroll
        for (int r=0; r<4; ++r) {
            int n = tb + w*32 + mt*16 + quad*4 + r;
            float val = acc[mt][r] + bv;
            float m = val;
            #pragma unroll
            for (int off=8; off>0; off>>=1) m = fmaxf(m, __shfl_xor(m, off, 16));
            float ex = __expf(val - m);
            float s = ex;
            #pragma unroll
            for (int off=8; off>0; off>>=1) s += __shfl_xor(s, off, 16);
            if (n < NN) Y[(long)n*CC + col] = val - m - __logf(s);
        }
    }
}

__global__ __launch_bounds__(256, 2) void layer_mfma_kernel(
    const bf16* __restrict__ X1, const bf16* __restrict__ X2,
    const float* __restrict__ H,
    const bf16* __restrict__ Wg, const float* __restrict__ bg,
    const bf16* __restrict__ Wh, const float* __restrict__ bh,
    float* __restrict__ Hout)
{
    const int t    = threadIdx.x;
    const int w    = t >> 6;
    const int lane = t & 63;
    const int col  = lane & 15;
    const int quad = lane >> 4;

    bf16x8 Bg[3][4];
    bf16x8 Bh[3][2];
    float bgv[3], bhv[3];
    #pragma unroll
    for (int jt=0; jt<3; ++jt) {
        int J = jt*64 + 16*w + col;
        #pragma unroll
        for (int ks=0; ks<4; ++ks)
            Bg[jt][ks] = *(const bf16x8*)&Wg[J*128 + ks*32 + quad*8];
        #pragma unroll
        for (int ks=0; ks<2; ++ks)
            Bh[jt][ks] = *(const bf16x8*)&Wh[J*64 + ks*32 + quad*8];
        bgv[jt] = bg[J];
        bhv[jt] = bh[J];
    }

    __shared__ bf16 Alds[32][200];

    const int m_st = t >> 3;
    const int c_in = t & 7;

    for (int tb = blockIdx.x*32; tb < NN; tb += gridDim.x*32) {
        {
            long n = tb + m_st;
            *(bf16x8*)&Alds[m_st][c_in*8]      = *(const bf16x8*)&X1[n*HH + c_in*8];
            *(bf16x8*)&Alds[m_st][64 + c_in*8] = *(const bf16x8*)&X2[n*HH + c_in*8];
            const float4* rh = (const float4*)&H[n*HH];
            float4 a = rh[c_in*2], b4 = rh[c_in*2+1];
            bf16x8 hb = {(bf16)a.x,(bf16)a.y,(bf16)a.z,(bf16)a.w,
                         (bf16)b4.x,(bf16)b4.y,(bf16)b4.z,(bf16)b4.w};
            *(bf16x8*)&Alds[m_st][128 + c_in*8] = hb;
        }
        __syncthreads();

        f32x4 accg[2][3];
        f32x4 acch[2][3];
        #pragma unroll
        for (int mt=0; mt<2; ++mt)
            #pragma unroll
            for (int jt=0; jt<3; ++jt) {
                accg[mt][jt] = (f32x4){0.f,0.f,0.f,0.f};
                acch[mt][jt] = (f32x4){0.f,0.f,0.f,0.f};
            }

        #pragma unroll
        for (int ks=0; ks<4; ++ks) {
            #pragma unroll
            for (int mt=0; mt<2; ++mt) {
                bf16x8 a = *(const bf16x8*)&Alds[mt*16 + col][ks*32 + quad*8];
                #pragma unroll
                for (int jt=0; jt<3; ++jt)
                    accg[mt][jt] = __builtin_amdgcn_mfma_f32_16x16x32_bf16(
                        a, Bg[jt][ks], accg[mt][jt], 0, 0, 0);
            }
        }
        #pragma unroll
        for (int ks=0; ks<2; ++ks) {
            #pragma unroll
            for (int mt=0; mt<2; ++mt) {
                bf16x8 a = *(const bf16x8*)&Alds[mt*16 + col][128 + ks*32 + quad*8];
                #pragma unroll
                for (int jt=0; jt<3; ++jt)
                    acch[mt][jt] = __builtin_amdgcn_mfma_f32_16x16x32_bf16(
                        a, Bh[jt][ks], acch[mt][jt], 0, 0, 0);
            }
        }
        __syncthreads();

        const int c = 16*w + col;
        #pragma unroll
        for (int mt=0; mt<2; ++mt) {
            #pragma unroll
            for (int r=0; r<4; ++r) {
                long n = tb + mt*16 + quad*4 + r;
                float gr = accg[mt][0][r] + bgv[0];
                float gz = accg[mt][1][r] + bgv[1];
                float gn = accg[mt][2][r] + bgv[2];
                float hr = acch[mt][0][r] + bhv[0];
                float hz = acch[mt][1][r] + bhv[1];
                float hn = acch[mt][2][r] + bhv[2];
                float rr = fsig(gr + hr);
                float zz = fsig(gz + hz);
                float nv = ftanh(gn + rr*hn);
                float hv = H[n*HH + c];
                Hout[n*HH + c] = (1.0f - zz)*nv + zz*hv;
            }
        }
    }
}

extern "C" void kernel_launch(void* const* d_in, const int* in_sizes, int n_in,
                              void* d_out, int out_size, void* d_ws, size_t ws_size,
                              hipStream_t stream)
{
    const float* x       = (const float*)d_in[0];
    const int*   ei      = (const int*)  d_in[1];
    const float* ew      = (const float*)d_in[2];
    const int*   ei_re   = (const int*)  d_in[3];
    const float* ew_re   = (const float*)d_in[4];
    const float* W_first = (const float*)d_in[5];
    const float* b_first = (const float*)d_in[6];
    const float* W_con1  = (const float*)d_in[7];
    const float* b_con1  = (const float*)d_in[8];
    const float* W_con2  = (const float*)d_in[9];
    const float* b_con2  = (const float*)d_in[10];
    const float* W_lin1  = (const float*)d_in[11];
    const float* b_lin1  = (const float*)d_in[12];
    const float* W_out   = (const float*)d_in[13];
    const float* b_out   = (const float*)d_in[14];
    const float* W_ih    = (const float*)d_in[15];
    const float* W_hh    = (const float*)d_in[16];
    const float* b_ih    = (const float*)d_in[17];
    const float* b_hh    = (const float*)d_in[18];
    float* out = (float*)d_out;

    // ---- workspace layout
    float* h    = (float*)d_ws;                // [N*64] fp32 GRU state
    float* hA   = h  + (long)NN*HH;            // [N*64] fp32 layer output
    bf16*  x1b  = (bf16*)(hA + (long)NN*HH);   // [N*64]
    bf16*  x2b  = x1b + (long)NN*HH;           // [N*64]
    bf16*  hbf  = x2b + (long)NN*HH;           // [N*64]
    bf16*  hAbf = hbf + (long)NN*HH;           // [N*64]
    float* b1 = (float*)(hAbf + (long)NN*HH);  // [192]
    float* b2 = b1 + 192;                      // [192]
    bf16*  W1bf = (bf16*)(b2 + 192);           // [192*128]
    bf16*  W2bf = W1bf + 192*128;
    bf16*  Whbf = W2bf + 192*128;
    bf16*  Wfbf = Whbf + 192*64;
    bf16*  Wlbf = Wfbf + 64*128;
    bf16*  Wobf = Wlbf + 64*64;
    int*   rp     = (int*)(Wobf + 16*64);      // [NSEG+1]
    int*   bkcnt  = rp + NSEG + 1;             // [NBUK]
    int*   bkbase = bkcnt + NBUK;              // [NBUK+1]
    int*   bkcur  = bkbase + NBUK + 1;         // [NBUK]
    unsigned* edata = (unsigned*)(bkcur + NBUK); // [2E] packed (src,w), dst-sorted
    int*      tmp_d = (int*)x1b;               // [2E] 8 MB (aliases, dead until fillB done)
    unsigned* tmp_p = (unsigned*)x2b;          // [2E] 8 MB

    // 0) weights in bf16 (+ fp32 biases)
    precomp_kernel<<<(192*128 + 192 + 192*64 + 64*128 + 64*64 + 16*64 + 255)/256, 256, 0, stream>>>(
        W_ih, b_ih, W_con1, b_con1, W_con2, b_con2, W_hh, W_first, W_lin1, W_out,
        W1bf, b1, W2bf, b2, Whbf, Wfbf, Wlbf, Wobf);

    // 1) CSR build: bucket-count -> 98-scan -> 2-phase sort (fillB also emits rp)
    hipMemsetAsync(bkcnt, 0, (size_t)NBUK*sizeof(int), stream);
    bucket_count_kernel<<<P1BLK, 256, 0, stream>>>(ei, ei_re, bkcnt);
    bucket_scan_kernel<<<1, 64, 0, stream>>>(bkcnt, bkbase, bkcur, rp);
    fillA_kernel<<<P1BLK, 256, 0, stream>>>(ei, ew, ei_re, ew_re, bkcur, tmp_d, tmp_p);
    fillB_kernel<<<NBUK, 1024, 0, stream>>>(bkbase, tmp_d, tmp_p, edata, rp);

    // 2) h = x @ W_first^T + b_first   (MFMA; fp32 + bf16 outputs)
    lin_first_mfma_kernel<<<1024, 256, 0, stream>>>(x, Wfbf, b_first, h, hbf);

    // 3) layer-1 propagation (quarter-wave bf16 gather)
    csr_prop_kernel<<<(NSEG + 3)/4, 256, 0, stream>>>(hbf, rp, edata, x1b, x2b);

    // 4) fused con1 + GRU -> hA   (MFMA)
    layer_mfma_kernel<<<1024, 256, 0, stream>>>(x1b, x2b, h, W1bf, b1, Whbf, b_hh, hA);

    // 5) lin1 -> hAbf (bf16, feeds prop only)
    lin64_mfma_kernel<<<1024, 256, 0, stream>>>(hA, Wlbf, b_lin1, hAbf);

    // 6) layer-2 propagation
    csr_prop_kernel<<<(NSEG + 3)/4, 256, 0, stream>>>(hAbf, rp, edata, x1b, x2b);

    // 7) fused con2 + GRU -> hA   (MFMA)
    layer_mfma_kernel<<<1024, 256, 0, stream>>>(x1b, x2b, h, W2bf, b2, Whbf, b_hh, hA);

    // 8) W_out + log_softmax   (MFMA)
    out_mfma_kernel<<<(NN + 127)/128, 256, 0, stream>>>(hA, Wobf, b_out, out);
}

// Round 10
// 415.088 us; speedup vs baseline: 1.1137x; 1.1137x over previous
//
#include <hip/hip_runtime.h>

#define NN 100000
#define FF 128
#define HH 64
#define CC 16
#define EE 1000000
#define NSEG (2*NN)                 // segments: [0,NN) = fwd, [NN,2NN) = rev
#define BSH 11                      // bucket = d >> 11 (2048 dsts/bucket)
#define BKD  (1 << BSH)
#define NBUK ((NSEG + BKD - 1) / BKD)   // 98
#define EPB 4096                    // edges per fillA/bucket_count block
#define P1BLK ((2*EE + EPB - 1) / EPB)

typedef __bf16 bf16;
typedef __attribute__((ext_vector_type(8))) __bf16 bf16x8;
typedef __attribute__((ext_vector_type(4))) __bf16 bf16x4;
typedef __attribute__((ext_vector_type(4))) float f32x4;

__device__ __forceinline__ float fsig(float t)  { return 1.0f/(1.0f+__expf(-t)); }
__device__ __forceinline__ float ftanh(float t) { return 1.0f - 2.0f/(__expf(2.0f*t)+1.0f); }

// pack (src, w>=0) into 4 B: src(17 bits) << 15 | bf16(w) sans sign (15 bits)
__device__ __forceinline__ unsigned pack_sw(int s, float w) {
    unsigned short u = __builtin_bit_cast(unsigned short, (bf16)w);
    return ((unsigned)s << 15) | (u & 0x7FFFu);
}

// ---- Combined weights in bf16 + bf16 copies of W_first / W_lin1 / W_out
__global__ void precomp_kernel(const float* __restrict__ W_ih, const float* __restrict__ b_ih,
                               const float* __restrict__ Wc1,  const float* __restrict__ bc1,
                               const float* __restrict__ Wc2,  const float* __restrict__ bc2,
                               const float* __restrict__ W_hh, const float* __restrict__ W_first,
                               const float* __restrict__ W_lin1, const float* __restrict__ W_out,
                               bf16* __restrict__ W1bf, float* __restrict__ b1,
                               bf16* __restrict__ W2bf, float* __restrict__ b2,
                               bf16* __restrict__ Whbf, bf16* __restrict__ Wfbf,
                               bf16* __restrict__ Wlbf, bf16* __restrict__ Wobf)
{
    int idx = blockIdx.x*blockDim.x + threadIdx.x;
    const int t0 = 192*128;          // W1/W2
    const int t1 = t0 + 192;         // b1/b2
    const int t2 = t1 + 192*64;      // Whbf
    const int t3 = t2 + 64*128;      // Wfbf
    const int t4 = t3 + 64*64;       // Wlbf
    const int t5 = t4 + 16*64;       // Wobf
    if (idx < t0) {
        int j = idx >> 7, k = idx & 127;
        float s1 = 0.f, s2 = 0.f;
        for (int m=0; m<64; ++m) {
            float wih = W_ih[j*64+m];
            s1 += wih * Wc1[m*128+k];
            s2 += wih * Wc2[m*128+k];
        }
        W1bf[idx] = (bf16)s1; W2bf[idx] = (bf16)s2;
    } else if (idx < t1) {
        int j = idx - t0;
        float s1 = b_ih[j], s2 = b_ih[j];
        for (int m=0; m<64; ++m) {
            float wih = W_ih[j*64+m];
            s1 += wih * bc1[m];
            s2 += wih * bc2[m];
        }
        b1[j] = s1; b2[j] = s2;
    } else if (idx < t2) {
        int i = idx - t1;  Whbf[i] = (bf16)W_hh[i];
    } else if (idx < t3) {
        int i = idx - t2;  Wfbf[i] = (bf16)W_first[i];
    } else if (idx < t4) {
        int i = idx - t3;  Wlbf[i] = (bf16)W_lin1[i];
    } else if (idx < t5) {
        int i = idx - t4;  Wobf[i] = (bf16)W_out[i];
    }
}

// ================= CSR build: bucketed 2-phase sort =================

__global__ __launch_bounds__(256) void bucket_count_kernel(const int* __restrict__ ei,
                                                           const int* __restrict__ ei_re,
                                                           int* __restrict__ bkcnt)
{
    __shared__ int hist[NBUK];
    const int t = threadIdx.x;
    for (int i=t; i<NBUK; i+=256) hist[i] = 0;
    __syncthreads();
    const long e0 = (long)blockIdx.x * EPB;
    #pragma unroll
    for (int it=0; it<16; ++it) {
        long e = e0 + it*256 + t;
        int d = -1;
        if (e < EE)        d = ei[EE + e];
        else if (e < 2*EE) d = NN + ei_re[EE + (e - EE)];
        if (d >= 0) atomicAdd(&hist[d >> BSH], 1);
    }
    __syncthreads();
    for (int i=t; i<NBUK; i+=256) if (hist[i]) atomicAdd(&bkcnt[i], hist[i]);
}

__global__ void bucket_scan_kernel(const int* __restrict__ bkcnt,
                                   int* __restrict__ bkbase, int* __restrict__ bkcur,
                                   int* __restrict__ rp)
{
    if (threadIdx.x == 0) {
        int acc = 0;
        for (int i=0; i<NBUK; ++i) { bkbase[i] = acc; bkcur[i] = acc; acc += bkcnt[i]; }
        bkbase[NBUK] = acc;          // = 2E
        rp[NSEG] = 2*EE;
    }
}

__global__ __launch_bounds__(256) void fillA_kernel(const int* __restrict__ ei,
                                                    const float* __restrict__ ew,
                                                    const int* __restrict__ ei_re,
                                                    const float* __restrict__ ew_re,
                                                    int* __restrict__ bkcur,
                                                    int* __restrict__ tmp_d,
                                                    unsigned* __restrict__ tmp_p)
{
    __shared__ int hist[NBUK];
    __shared__ int base[NBUK];
    const int t = threadIdx.x;
    for (int i=t; i<NBUK; i+=256) hist[i] = 0;
    __syncthreads();
    const long e0 = (long)blockIdx.x * EPB;
    int pr[16];
    #pragma unroll
    for (int it=0; it<16; ++it) {
        long e = e0 + it*256 + t;
        int d = -1;
        if (e < EE)        d = ei[EE + e];
        else if (e < 2*EE) d = NN + ei_re[EE + (e - EE)];
        if (d >= 0) {
            int b = d >> BSH;
            int r = atomicAdd(&hist[b], 1);
            pr[it] = (b << 16) | r;
        } else pr[it] = -1;
    }
    __syncthreads();
    for (int i=t; i<NBUK; i+=256) base[i] = atomicAdd(&bkcur[i], hist[i]);
    __syncthreads();
    #pragma unroll
    for (int it=0; it<16; ++it) {
        if (pr[it] < 0) continue;
        long e = e0 + it*256 + t;
        int d, s; float w;
        if (e < EE) { d = ei[EE+e]; s = ei[e]; w = ew[e]; }
        else { long j = e - EE; d = NN + ei_re[EE+j]; s = ei_re[j]; w = ew_re[j]; }
        int pos = base[pr[it] >> 16] + (pr[it] & 0xFFFF);
        tmp_d[pos] = d;
        tmp_p[pos] = pack_sw(s, w);
    }
}

__global__ __launch_bounds__(1024) void fillB_kernel(const int* __restrict__ bkbase,
                                                     const int* __restrict__ tmp_d,
                                                     const unsigned* __restrict__ tmp_p,
                                                     unsigned* __restrict__ edata,
                                                     int* __restrict__ rp)
{
    __shared__ int cntL[BKD];      // counts -> later global cursors
    __shared__ int scanL[1024];
    const int t  = threadIdx.x;
    const int b  = blockIdx.x;
    const int d0 = b << BSH;
    const int dn = min(BKD, NSEG - d0);
    const int p0 = bkbase[b];
    const int p1 = bkbase[b+1];
    for (int i=t; i<BKD; i+=1024) cntL[i] = 0;
    __syncthreads();
    for (int pos = p0 + t; pos < p1; pos += 1024)
        atomicAdd(&cntL[tmp_d[pos] - d0], 1);
    __syncthreads();
    int a0 = cntL[2*t], a1 = cntL[2*t+1];
    int ps = a0 + a1;
    scanL[t] = ps;
    __syncthreads();
    #pragma unroll
    for (int off=1; off<1024; off<<=1) {
        int x = (t>=off) ? scanL[t-off] : 0;
        __syncthreads();
        scanL[t] += x;
        __syncthreads();
    }
    int g0 = p0 + scanL[t] - ps;
    int g1 = g0 + a0;
    if (2*t   < dn) rp[d0 + 2*t]   = g0;
    if (2*t+1 < dn) rp[d0 + 2*t+1] = g1;
    cntL[2*t]   = g0;
    cntL[2*t+1] = g1;
    __syncthreads();
    for (int pos = p0 + t; pos < p1; pos += 1024) {
        int d = tmp_d[pos];
        int p = atomicAdd(&cntL[d - d0], 1);
        edata[p] = tmp_p[pos];
    }
}

// Quarter-wave gather segment-sum, 4-deep unrolled: 16 lanes/edge, 16 edge
// slots per loop pass -> ~5 VALU/edge (R8 full-wave: ~9, VALUBusy 86%) AND
// 4 independent X gathers in flight (R9 1-deep: latency-bound, VALUBusy 40%).
__global__ __launch_bounds__(256) void csr_prop_kernel(const bf16* __restrict__ X,
    const int* __restrict__ rp, const unsigned* __restrict__ edata,
    bf16* __restrict__ x1, bf16* __restrict__ x2)
{
    int s = blockIdx.x*4 + (threadIdx.x>>6);
    if (s >= NSEG) return;
    const int lane = threadIdx.x & 63;
    const int q  = lane >> 4;      // edge slot 0..3
    const int fl = lane & 15;      // feature group: 4fl .. 4fl+3
    const int e0 = rp[s], e1 = rp[s+1];
    float a0=0.f, a1=0.f, a2=0.f, a3=0.f;
    for (int base = e0; base < e1; base += 16) {
        unsigned pk[4]; float vw[4];
        #pragma unroll
        for (int j=0;j<4;++j) {
            int e = base + j*4 + q;
            unsigned p = edata[e < e1 ? e : e0];
            pk[j] = p;
            vw[j] = (e < e1) ? __uint_as_float((p & 0x7FFFu) << 16) : 0.f;
        }
        bf16x4 xv[4];
        #pragma unroll
        for (int j=0;j<4;++j)
            xv[j] = *(const bf16x4*)&X[(long)(pk[j] >> 15)*HH + 4*fl];
        #pragma unroll
        for (int j=0;j<4;++j) {
            a0 += vw[j]*(float)xv[j][0];
            a1 += vw[j]*(float)xv[j][1];
            a2 += vw[j]*(float)xv[j][2];
            a3 += vw[j]*(float)xv[j][3];
        }
    }
    // reduce across the 4 quarters (lanes with equal fl)
    a0 += __shfl_xor(a0, 32); a0 += __shfl_xor(a0, 16);
    a1 += __shfl_xor(a1, 32); a1 += __shfl_xor(a1, 16);
    a2 += __shfl_xor(a2, 32); a2 += __shfl_xor(a2, 16);
    a3 += __shfl_xor(a3, 32); a3 += __shfl_xor(a3, 16);
    if (q == 0) {
        bf16* o = (s < NN) ? &x1[(long)s*HH] : &x2[(long)(s-NN)*HH];
        bf16x4 ov = {(bf16)a0, (bf16)a1, (bf16)a2, (bf16)a3};
        *(bf16x4*)&o[4*fl] = ov;
    }
}

// ================= dense kernels: all MFMA (unchanged) =================

__global__ __launch_bounds__(256, 2) void lin_first_mfma_kernel(
    const float* __restrict__ X, const bf16* __restrict__ Wf,
    const float* __restrict__ b, float* __restrict__ Y, bf16* __restrict__ Ybf)
{
    const int t = threadIdx.x;
    const int w = t >> 6, lane = t & 63, col = lane & 15, quad = lane >> 4;
    bf16x8 B[4];
    #pragma unroll
    for (int ks=0; ks<4; ++ks)
        B[ks] = *(const bf16x8*)&Wf[(16*w+col)*128 + ks*32 + quad*8];
    const float bv = b[16*w + col];
    __shared__ bf16 Alds[32][136];
    const int m_st = t >> 3, c_in = t & 7;
    for (int tb = blockIdx.x*32; tb < NN; tb += gridDim.x*32) {
        const float4* rx = (const float4*)&X[(long)(tb+m_st)*FF];
        #pragma unroll
        for (int it=0; it<4; ++it) {
            int cc = c_in + it*8;
            float4 v = rx[cc];
            bf16x4 bvv = {(bf16)v.x,(bf16)v.y,(bf16)v.z,(bf16)v.w};
            *(bf16x4*)&Alds[m_st][cc*4] = bvv;
        }
        __syncthreads();
        f32x4 acc[2] = {{0.f,0.f,0.f,0.f},{0.f,0.f,0.f,0.f}};
        #pragma unroll
        for (int ks=0; ks<4; ++ks)
            #pragma unroll
            for (int mt=0; mt<2; ++mt) {
                bf16x8 a = *(const bf16x8*)&Alds[mt*16+col][ks*32+quad*8];
                acc[mt] = __builtin_amdgcn_mfma_f32_16x16x32_bf16(a, B[ks], acc[mt], 0,0,0);
            }
        __syncthreads();
        #pragma unroll
        for (int mt=0; mt<2; ++mt)
            #pragma unroll
            for (int r=0; r<4; ++r) {
                long n = tb + mt*16 + quad*4 + r;
                float val = acc[mt][r] + bv;
                Y  [n*HH + 16*w+col] = val;
                Ybf[n*HH + 16*w+col] = (bf16)val;
            }
    }
}

__global__ __launch_bounds__(256, 2) void lin64_mfma_kernel(
    const float* __restrict__ X, const bf16* __restrict__ Wl,
    const float* __restrict__ b, bf16* __restrict__ Ybf)
{
    const int t = threadIdx.x;
    const int w = t >> 6, lane = t & 63, col = lane & 15, quad = lane >> 4;
    bf16x8 B[2];
    #pragma unroll
    for (int ks=0; ks<2; ++ks)
        B[ks] = *(const bf16x8*)&Wl[(16*w+col)*64 + ks*32 + quad*8];
    const float bv = b[16*w + col];
    __shared__ bf16 Alds[32][72];
    const int m_st = t >> 3, c_in = t & 7;
    for (int tb = blockIdx.x*32; tb < NN; tb += gridDim.x*32) {
        const float4* rx = (const float4*)&X[(long)(tb+m_st)*HH];
        #pragma unroll
        for (int it=0; it<2; ++it) {
            int cc = c_in + it*8;
            float4 v = rx[cc];
            bf16x4 bvv = {(bf16)v.x,(bf16)v.y,(bf16)v.z,(bf16)v.w};
            *(bf16x4*)&Alds[m_st][cc*4] = bvv;
        }
        __syncthreads();
        f32x4 acc[2] = {{0.f,0.f,0.f,0.f},{0.f,0.f,0.f,0.f}};
        #pragma unroll
        for (int ks=0; ks<2; ++ks)
            #pragma unroll
            for (int mt=0; mt<2; ++mt) {
                bf16x8 a = *(const bf16x8*)&Alds[mt*16+col][ks*32+quad*8];
                acc[mt] = __builtin_amdgcn_mfma_f32_16x16x32_bf16(a, B[ks], acc[mt], 0,0,0);
            }
        __syncthreads();
        #pragma unroll
        for (int mt=0; mt<2; ++mt)
            #pragma unroll
            for (int r=0; r<4; ++r)
                Ybf[(long)(tb+mt*16+quad*4+r)*HH + 16*w+col] = (bf16)(acc[mt][r] + bv);
    }
}

__global__ __launch_bounds__(256) void out_mfma_kernel(
    const float* __restrict__ X, const bf16* __restrict__ Wo,
    const float* __restrict__ b, float* __restrict__ Y)
{
    const int t = threadIdx.x;
    const int w = t >> 6, lane = t & 63, col = lane & 15, quad = lane >> 4;
    bf16x8 B[2];
    #pragma unroll
    for (int ks=0; ks<2; ++ks)
        B[ks] = *(const bf16x8*)&Wo[col*64 + ks*32 + quad*8];
    const float bv = b[col];
    __shared__ bf16 Alds[128][72];
    const int r_st = t >> 1, sub = t & 1;
    const int tb = blockIdx.x*128;
    {
        const float4* rx = (const float4*)&X[(long)(tb+r_st)*HH];
        #pragma unroll
        for (int it=0; it<8; ++it) {
            int cc = sub*8 + it;
            float4 v = rx[cc];
            bf16x4 bvv = {(bf16)v.x,(bf16)v.y,(bf16)v.z,(bf16)v.w};
            *(bf16x4*)&Alds[r_st][cc*4] = bvv;
        }
    }
    __syncthreads();
    f32x4 acc[2] = {{0.f,0.f,0.f,0.f},{0.f,0.f,0.f,0.f}};
    #pragma unroll
    for (int ks=0; ks<2; ++ks)
        #pragma unroll
        for (int mt=0; mt<2; ++mt) {
            bf16x8 a = *(const bf16x8*)&Alds[w*32 + mt*16 + col][ks*32+quad*8];
            acc[mt] = __builtin_amdgcn_mfma_f32_16x16x32_bf16(a, B[ks], acc[mt], 0,0,0);
        }
    #pragma unroll
    for (int mt=0; mt<2; ++mt) {
        #pragma unroll
        for (int r=0; r<4; ++r) {
            int n = tb + w*32 + mt*16 + quad*4 + r;
            float val = acc[mt][r] + bv;
            float m = val;
            #pragma unroll
            for (int off=8; off>0; off>>=1) m = fmaxf(m, __shfl_xor(m, off, 16));
            float ex = __expf(val - m);
            float s = ex;
            #pragma unroll
            for (int off=8; off>0; off>>=1) s += __shfl_xor(s, off, 16);
            if (n < NN) Y[(long)n*CC + col] = val - m - __logf(s);
        }
    }
}

__global__ __launch_bounds__(256, 2) void layer_mfma_kernel(
    const bf16* __restrict__ X1, const bf16* __restrict__ X2,
    const float* __restrict__ H,
    const bf16* __restrict__ Wg, const float* __restrict__ bg,
    const bf16* __restrict__ Wh, const float* __restrict__ bh,
    float* __restrict__ Hout)
{
    const int t    = threadIdx.x;
    const int w    = t >> 6;
    const int lane = t & 63;
    const int col  = lane & 15;
    const int quad = lane >> 4;

    bf16x8 Bg[3][4];
    bf16x8 Bh[3][2];
    float bgv[3], bhv[3];
    #pragma unroll
    for (int jt=0; jt<3; ++jt) {
        int J = jt*64 + 16*w + col;
        #pragma unroll
        for (int ks=0; ks<4; ++ks)
            Bg[jt][ks] = *(const bf16x8*)&Wg[J*128 + ks*32 + quad*8];
        #pragma unroll
        for (int ks=0; ks<2; ++ks)
            Bh[jt][ks] = *(const bf16x8*)&Wh[J*64 + ks*32 + quad*8];
        bgv[jt] = bg[J];
        bhv[jt] = bh[J];
    }

    __shared__ bf16 Alds[32][200];

    const int m_st = t >> 3;
    const int c_in = t & 7;

    for (int tb = blockIdx.x*32; tb < NN; tb += gridDim.x*32) {
        {
            long n = tb + m_st;
            *(bf16x8*)&Alds[m_st][c_in*8]      = *(const bf16x8*)&X1[n*HH + c_in*8];
            *(bf16x8*)&Alds[m_st][64 + c_in*8] = *(const bf16x8*)&X2[n*HH + c_in*8];
            const float4* rh = (const float4*)&H[n*HH];
            float4 a = rh[c_in*2], b4 = rh[c_in*2+1];
            bf16x8 hb = {(bf16)a.x,(bf16)a.y,(bf16)a.z,(bf16)a.w,
                         (bf16)b4.x,(bf16)b4.y,(bf16)b4.z,(bf16)b4.w};
            *(bf16x8*)&Alds[m_st][128 + c_in*8] = hb;
        }
        __syncthreads();

        f32x4 accg[2][3];
        f32x4 acch[2][3];
        #pragma unroll
        for (int mt=0; mt<2; ++mt)
            #pragma unroll
            for (int jt=0; jt<3; ++jt) {
                accg[mt][jt] = (f32x4){0.f,0.f,0.f,0.f};
                acch[mt][jt] = (f32x4){0.f,0.f,0.f,0.f};
            }

        #pragma unroll
        for (int ks=0; ks<4; ++ks) {
            #pragma unroll
            for (int mt=0; mt<2; ++mt) {
                bf16x8 a = *(const bf16x8*)&Alds[mt*16 + col][ks*32 + quad*8];
                #pragma unroll
                for (int jt=0; jt<3; ++jt)
                    accg[mt][jt] = __builtin_amdgcn_mfma_f32_16x16x32_bf16(
                        a, Bg[jt][ks], accg[mt][jt], 0, 0, 0);
            }
        }
        #pragma unroll
        for (int ks=0; ks<2; ++ks) {
            #pragma unroll
            for (int mt=0; mt<2; ++mt) {
                bf16x8 a = *(const bf16x8*)&Alds[mt*16 + col][128 + ks*32 + quad*8];
                #pragma unroll
                for (int jt=0; jt<3; ++jt)
                    acch[mt][jt] = __builtin_amdgcn_mfma_f32_16x16x32_bf16(
                        a, Bh[jt][ks], acch[mt][jt], 0, 0, 0);
            }
        }
        __syncthreads();

        const int c = 16*w + col;
        #pragma unroll
        for (int mt=0; mt<2; ++mt) {
            #pragma unroll
            for (int r=0; r<4; ++r) {
                long n = tb + mt*16 + quad*4 + r;
                float gr = accg[mt][0][r] + bgv[0];
                float gz = accg[mt][1][r] + bgv[1];
                float gn = accg[mt][2][r] + bgv[2];
                float hr = acch[mt][0][r] + bhv[0];
                float hz = acch[mt][1][r] + bhv[1];
                float hn = acch[mt][2][r] + bhv[2];
                float rr = fsig(gr + hr);
                float zz = fsig(gz + hz);
                float nv = ftanh(gn + rr*hn);
                float hv = H[n*HH + c];
                Hout[n*HH + c] = (1.0f - zz)*nv + zz*hv;
            }
        }
    }
}

extern "C" void kernel_launch(void* const* d_in, const int* in_sizes, int n_in,
                              void* d_out, int out_size, void* d_ws, size_t ws_size,
                              hipStream_t stream)
{
    const float* x       = (const float*)d_in[0];
    const int*   ei      = (const int*)  d_in[1];
    const float* ew      = (const float*)d_in[2];
    const int*   ei_re   = (const int*)  d_in[3];
    const float* ew_re   = (const float*)d_in[4];
    const float* W_first = (const float*)d_in[5];
    const float* b_first = (const float*)d_in[6];
    const float* W_con1  = (const float*)d_in[7];
    const float* b_con1  = (const float*)d_in[8];
    const float* W_con2  = (const float*)d_in[9];
    const float* b_con2  = (const float*)d_in[10];
    const float* W_lin1  = (const float*)d_in[11];
    const float* b_lin1  = (const float*)d_in[12];
    const float* W_out   = (const float*)d_in[13];
    const float* b_out   = (const float*)d_in[14];
    const float* W_ih    = (const float*)d_in[15];
    const float* W_hh    = (const float*)d_in[16];
    const float* b_ih    = (const float*)d_in[17];
    const float* b_hh    = (const float*)d_in[18];
    float* out = (float*)d_out;

    // ---- workspace layout
    float* h    = (float*)d_ws;                // [N*64] fp32 GRU state
    float* hA   = h  + (long)NN*HH;            // [N*64] fp32 layer output
    bf16*  x1b  = (bf16*)(hA + (long)NN*HH);   // [N*64]
    bf16*  x2b  = x1b + (long)NN*HH;           // [N*64]
    bf16*  hbf  = x2b + (long)NN*HH;           // [N*64]
    bf16*  hAbf = hbf + (long)NN*HH;           // [N*64]
    float* b1 = (float*)(hAbf + (long)NN*HH);  // [192]
    float* b2 = b1 + 192;                      // [192]
    bf16*  W1bf = (bf16*)(b2 + 192);           // [192*128]
    bf16*  W2bf = W1bf + 192*128;
    bf16*  Whbf = W2bf + 192*128;
    bf16*  Wfbf = Whbf + 192*64;
    bf16*  Wlbf = Wfbf + 64*128;
    bf16*  Wobf = Wlbf + 64*64;
    int*   rp     = (int*)(Wobf + 16*64);      // [NSEG+1]
    int*   bkcnt  = rp + NSEG + 1;             // [NBUK]
    int*   bkbase = bkcnt + NBUK;              // [NBUK+1]
    int*   bkcur  = bkbase + NBUK + 1;         // [NBUK]
    unsigned* edata = (unsigned*)(bkcur + NBUK); // [2E] packed (src,w), dst-sorted
    int*      tmp_d = (int*)x1b;               // [2E] 8 MB (aliases, dead until fillB done)
    unsigned* tmp_p = (unsigned*)x2b;          // [2E] 8 MB

    // 0) weights in bf16 (+ fp32 biases)
    precomp_kernel<<<(192*128 + 192 + 192*64 + 64*128 + 64*64 + 16*64 + 255)/256, 256, 0, stream>>>(
        W_ih, b_ih, W_con1, b_con1, W_con2, b_con2, W_hh, W_first, W_lin1, W_out,
        W1bf, b1, W2bf, b2, Whbf, Wfbf, Wlbf, Wobf);

    // 1) CSR build: bucket-count -> 98-scan -> 2-phase sort (fillB also emits rp)
    hipMemsetAsync(bkcnt, 0, (size_t)NBUK*sizeof(int), stream);
    bucket_count_kernel<<<P1BLK, 256, 0, stream>>>(ei, ei_re, bkcnt);
    bucket_scan_kernel<<<1, 64, 0, stream>>>(bkcnt, bkbase, bkcur, rp);
    fillA_kernel<<<P1BLK, 256, 0, stream>>>(ei, ew, ei_re, ew_re, bkcur, tmp_d, tmp_p);
    fillB_kernel<<<NBUK, 1024, 0, stream>>>(bkbase, tmp_d, tmp_p, edata, rp);

    // 2) h = x @ W_first^T + b_first   (MFMA; fp32 + bf16 outputs)
    lin_first_mfma_kernel<<<1024, 256, 0, stream>>>(x, Wfbf, b_first, h, hbf);

    // 3) layer-1 propagation (quarter-wave, 4-deep unroll)
    csr_prop_kernel<<<(NSEG + 3)/4, 256, 0, stream>>>(hbf, rp, edata, x1b, x2b);

    // 4) fused con1 + GRU -> hA   (MFMA)
    layer_mfma_kernel<<<1024, 256, 0, stream>>>(x1b, x2b, h, W1bf, b1, Whbf, b_hh, hA);

    // 5) lin1 -> hAbf (bf16, feeds prop only)
    lin64_mfma_kernel<<<1024, 256, 0, stream>>>(hA, Wlbf, b_lin1, hAbf);

    // 6) layer-2 propagation
    csr_prop_kernel<<<(NSEG + 3)/4, 256, 0, stream>>>(hAbf, rp, edata, x1b, x2b);

    // 7) fused con2 + GRU -> hA   (MFMA)
    layer_mfma_kernel<<<1024, 256, 0, stream>>>(x1b, x2b, h, W2bf, b2, Whbf, b_hh, hA);

    // 8) W_out + log_softmax   (MFMA)
    out_mfma_kernel<<<(NN + 127)/128, 256, 0, stream>>>(hA, Wobf, b_out, out);
}